// Round 9
// baseline (874.262 us; speedup 1.0000x reference)
//
#include <hip/hip_runtime.h>

#define D_ 512
#define ND_ 2048   // 4*D
#define KS_ 24
#define TB_ 32
#define B_ 8192
#define NU_ 33     // 32 K-units of Wu + 1 ext unit [Wx; b]

typedef __attribute__((ext_vector_type(8))) short short8;
typedef __attribute__((ext_vector_type(16))) float f32x16;
typedef unsigned short u16;

// byte offset into swizzled h tile: row in [0,32), kb = byte offset along d (d*2)
#define SWZ(row, kb) (((row) * 1024) + ((kb) ^ (((row) & 15) << 4)))

__device__ __forceinline__ u16 f2bf(float f) {
  union { float f; unsigned int u; } v; v.f = f;
  unsigned int u = v.u;
  return (u16)((u + 0x7FFFu + ((u >> 16) & 1u)) >> 16);
}

__device__ __forceinline__ float sigm(float x) { return 1.0f / (1.0f + __expf(-x)); }
__device__ __forceinline__ float tanh_(float x) {
  float e = __expf(2.0f * x);
  return (e - 1.0f) / (e + 1.0f);
}

// async global->LDS, 16 B per lane; LDS dest is wave-uniform base + lane*16
__device__ __forceinline__ void glds16(const u16* g, void* l) {
  __builtin_amdgcn_global_load_lds(
      (const __attribute__((address_space(1))) unsigned int*)g,
      (__attribute__((address_space(3))) unsigned int*)l, 16, 0, 0);
}

// Pack [Wu; Wx; b] into MFMA B-fragment order, bf16. (unchanged from R8)
__global__ __launch_bounds__(256) void pack_wu_kernel(const float* __restrict__ Wu,
                                                      const float* __restrict__ Wx,
                                                      const float* __restrict__ b,
                                                      u16* __restrict__ pk) {
  int idx = blockIdx.x * 256 + threadIdx.x;
  int lane = idx & 63;
  int unit = idx >> 6;        // 0..2111 = nt*33 + un
  if (unit >= 64 * NU_) return;
  int nt = unit / NU_;
  int un = unit - nt * NU_;
  int col = nt * 32 + (lane & 31);
  u16 t[8] = {0, 0, 0, 0, 0, 0, 0, 0};
  if (un < 32) {
    int k0 = un * 16 + (lane >> 5) * 8;
#pragma unroll
    for (int j = 0; j < 8; ++j) t[j] = f2bf(Wu[(size_t)(k0 + j) * ND_ + col]);
  } else if ((lane >> 5) == 0) {
    t[0] = f2bf(Wx[col]);
    t[1] = f2bf(b[col]);
  }
  int4 w;
  w.x = t[0] | (t[1] << 16); w.y = t[2] | (t[3] << 16);
  w.z = t[4] | (t[5] << 16); w.w = t[6] | (t[7] << 16);
  *reinterpret_cast<int4*>(pk + (size_t)unit * 512 + lane * 8) = w;
}

// one K-slice consume+issue: pb = gate-pair (0: gates i,f; 1: gates g,o)
#define KSTEP_PASS(CREG, COL, W1V, W2V, A0, A1, A2, A3, X0, X1, X2, X3)        \
  {                                                                            \
    acc0 = (f32x16){}; acc1 = (f32x16){}; acc2 = (f32x16){}; acc3 = (f32x16){};\
    _Pragma("unroll 1")                                                        \
    for (int ks = 0; ks < 33; ++ks) {                                          \
      int iks = ks + 2; int swp = 0;                                           \
      if (iks >= 33) { iks -= 33; swp = 1; }                                   \
      const size_t io = (size_t)iks * 512 + lofs8;                             \
      /* pb=0: issue pair(iks,0), wait, consume pair(ks,0) */                  \
      glds16((swp ? X0 : A0) + io, stg + slot_i * 2048);                       \
      glds16((swp ? X1 : A1) + io, stg + slot_i * 2048 + 1024);                \
      slot_i = (slot_i == 4) ? 0 : slot_i + 1;                                 \
      asm volatile("s_waitcnt vmcnt(8)" ::: "memory");                         \
      short8 a;                                                                \
      if (ks < 32) {                                                           \
        a = *reinterpret_cast<const short8*>(&hr[SWZ(l31, ks * 32 + abase)]);  \
      } else {                                                                 \
        short8 z8 = {};                                                        \
        if (lhi == 0) {                                                        \
          z8[0] = (short)f2bf(x_lds[l31]);                                     \
          z8[1] = (short)0x3F80;                                               \
        }                                                                      \
        a = z8;                                                                \
      }                                                                        \
      short8 f0 = *reinterpret_cast<const short8*>(stg + slot_c * 2048 + lofs);\
      short8 f1 = *reinterpret_cast<const short8*>(stg + slot_c * 2048 + 1024 + lofs);\
      slot_c = (slot_c == 4) ? 0 : slot_c + 1;                                 \
      acc0 = __builtin_amdgcn_mfma_f32_32x32x16_bf16(a, f0, acc0, 0, 0, 0);    \
      acc1 = __builtin_amdgcn_mfma_f32_32x32x16_bf16(a, f1, acc1, 0, 0, 0);    \
      /* pb=1 */                                                               \
      glds16((swp ? X2 : A2) + io, stg + slot_i * 2048);                       \
      glds16((swp ? X3 : A3) + io, stg + slot_i * 2048 + 1024);                \
      slot_i = (slot_i == 4) ? 0 : slot_i + 1;                                 \
      asm volatile("s_waitcnt vmcnt(8)" ::: "memory");                         \
      short8 f2 = *reinterpret_cast<const short8*>(stg + slot_c * 2048 + lofs);\
      short8 f3 = *reinterpret_cast<const short8*>(stg + slot_c * 2048 + 1024 + lofs);\
      slot_c = (slot_c == 4) ? 0 : slot_c + 1;                                 \
      acc2 = __builtin_amdgcn_mfma_f32_32x32x16_bf16(a, f2, acc2, 0, 0, 0);    \
      acc3 = __builtin_amdgcn_mfma_f32_32x32x16_bf16(a, f3, acc3, 0, 0, 0);    \
    }                                                                          \
    _Pragma("unroll")                                                          \
    for (int r = 0; r < 16; ++r) {                                             \
      const int row = (r & 3) + 8 * (r >> 2) + 4 * lhi;                        \
      float ig = sigm(acc0[r]);                                                \
      float fg = sigm(acc1[r]);                                                \
      float gg = tanh_(acc2[r]);                                               \
      float og = sigm(acc3[r]);                                                \
      float cn = fg * CREG[r] + ig * gg;                                       \
      CREG[r] = cn;                                                            \
      float hn = og * tanh_(cn);                                               \
      *reinterpret_cast<u16*>(&hw[SWZ(row, (COL) * 2)]) = f2bf(hn);            \
      y1p[r] += hn * (W1V);                                                    \
      y2p[r] += hn * (W2V);                                                    \
    }                                                                          \
  }

// 256 blocks x 512 threads (8 waves, 1 block/CU by LDS -> 2 waves/SIMD,
// 256-reg budget: acc 64 AGPR + ~110 VGPR, no spill). Each wave covers 2
// n-tiles per gate in two sequential passes (acc reused). Wu streamed via
// global_load_lds into a 5-slot/wave LDS ring with vmcnt(8) counted waits:
// issue->use lead = 4 pairs (~2 iters) covers L2 and most HBM latency; the
// cursor wraps across passes AND steps (same addresses every step) so the
// pipeline never drains.
__global__ __launch_bounds__(512, 2) void lstm_kernel(
    const float* __restrict__ initial, const float* __restrict__ enc_h,
    const float* __restrict__ enc_c,
    const float* __restrict__ w1, const float* __restrict__ b1,
    const float* __restrict__ w2, const float* __restrict__ b2,
    const u16* __restrict__ wu, float* __restrict__ out) {
  __shared__ __align__(16) unsigned char hbuf[2][TB_ * 1024];   // 64 KB h dbuf
  __shared__ __align__(16) unsigned char wu_stage[8 * 5 * 2048]; // 80 KB ring
  __shared__ float x_lds[TB_];
  __shared__ float ly1[8][TB_];
  __shared__ float ly2[8][TB_];

  const int tid = threadIdx.x;
  const int wv  = tid >> 6;
  const int wvu = __builtin_amdgcn_readfirstlane(wv);  // wave-uniform -> SGPR
  const int l   = tid & 63;
  const int l31 = l & 31;
  const int lhi = l >> 5;
  const int b0  = blockIdx.x * TB_;

  // ---- stage initial h (bf16, swizzled) into LDS: 512 threads ----
  {
    int row = tid >> 4;   // 0..31
    int seg = tid & 15;   // 32 cols each
    const float* src = enc_h + (size_t)(b0 + row) * D_ + seg * 32;
#pragma unroll
    for (int jb = 0; jb < 4; ++jb) {
      u16 t[8];
#pragma unroll
      for (int j = 0; j < 8; ++j) t[j] = f2bf(src[jb * 8 + j]);
      int kb = seg * 64 + jb * 16;
      int4 w;
      w.x = t[0] | (t[1] << 16); w.y = t[2] | (t[3] << 16);
      w.z = t[4] | (t[5] << 16); w.w = t[6] | (t[7] << 16);
      *reinterpret_cast<int4*>(&hbuf[0][SWZ(row, kb)]) = w;
    }
  }
  if (tid < TB_) x_lds[tid] = initial[b0 + tid];

  // ---- per-lane step-invariant values (2 passes) ----
  const int colA = wvu * 32 + l31;          // pass 0: n-tile wvu
  const int colB = (8 + wvu) * 32 + l31;    // pass 1: n-tile 8+wvu
  const float w1vA = w1[colA], w1vB = w1[colB];
  const float w2vA = w2[colA], w2vB = w2[colB];
  const float b1v = b1[0], b2v = b2[0];

  float cregA[16], cregB[16];
#pragma unroll
  for (int r = 0; r < 16; ++r) {
    const int row = (r & 3) + 8 * (r >> 2) + 4 * lhi;
    cregA[r] = enc_c[(size_t)(b0 + row) * D_ + colA];
    cregB[r] = enc_c[(size_t)(b0 + row) * D_ + colB];
  }

  // wave-uniform Wu stream bases: pass P, gate g -> n-tile g*16 + P*8 + wvu
  const u16* wA0 = wu + (size_t)(( 0 + wvu) * NU_) * 512;
  const u16* wA1 = wu + (size_t)((16 + wvu) * NU_) * 512;
  const u16* wA2 = wu + (size_t)((32 + wvu) * NU_) * 512;
  const u16* wA3 = wu + (size_t)((48 + wvu) * NU_) * 512;
  const u16* wB0 = wu + (size_t)(( 8 + wvu) * NU_) * 512;
  const u16* wB1 = wu + (size_t)((24 + wvu) * NU_) * 512;
  const u16* wB2 = wu + (size_t)((40 + wvu) * NU_) * 512;
  const u16* wB3 = wu + (size_t)((56 + wvu) * NU_) * 512;
  const size_t lofs8 = (size_t)l * 8;
  const int lofs = l * 16;
  const int abase = lhi * 16;
  unsigned char* stg = &wu_stage[wvu * 10240];  // 5 slots x 2 KB

  __syncthreads();
  asm volatile("s_waitcnt vmcnt(0)" ::: "memory");  // drain creg/h loads

  // prologue: issue pairs 0..3 (pass 0, ks 0..1, both gate-pairs)
  glds16(wA0 + lofs8, stg);
  glds16(wA1 + lofs8, stg + 1024);
  glds16(wA2 + lofs8, stg + 2048);
  glds16(wA3 + lofs8, stg + 3072);
  glds16(wA0 + 512 + lofs8, stg + 4096);
  glds16(wA1 + 512 + lofs8, stg + 5120);
  glds16(wA2 + 512 + lofs8, stg + 6144);
  glds16(wA3 + 512 + lofs8, stg + 7168);
  int slot_i = 4, slot_c = 0;

  for (int s = 0; s < KS_; ++s) {
    const unsigned char* hr = hbuf[s & 1];
    unsigned char* hw = hbuf[(s & 1) ^ 1];

    float y1p[16], y2p[16];
#pragma unroll
    for (int r = 0; r < 16; ++r) { y1p[r] = 0.f; y2p[r] = 0.f; }

    f32x16 acc0, acc1, acc2, acc3;
    // pass 0 (issue cursor rolls into pass-1 bases near the end)
    KSTEP_PASS(cregA, colA, w1vA, w2vA, wA0, wA1, wA2, wA3, wB0, wB1, wB2, wB3)
    // pass 1 (issue cursor wraps into pass-0 bases = next step's first pairs)
    KSTEP_PASS(cregB, colB, w1vB, w2vB, wB0, wB1, wB2, wB3, wA0, wA1, wA2, wA3)

    // reduce y partials across the 32 lanes of each half-wave
#pragma unroll
    for (int m = 1; m < 32; m <<= 1) {
#pragma unroll
      for (int r = 0; r < 16; ++r) {
        y1p[r] += __shfl_xor(y1p[r], m);
        y2p[r] += __shfl_xor(y2p[r], m);
      }
    }
    if (l31 == 0) {
#pragma unroll
      for (int r = 0; r < 16; ++r) {
        const int row = (r & 3) + 8 * (r >> 2) + 4 * lhi;
        ly1[wvu][row] = y1p[r];
        ly2[wvu][row] = y2p[r];
      }
    }
    __syncthreads();  // (1) ly slots + new h complete

    if (tid < TB_) {
      float s1 = b1v, s2 = b2v;
#pragma unroll
      for (int wq = 0; wq < 8; ++wq) { s1 += ly1[wq][tid]; s2 += ly2[wq][tid]; }
      float y1 = sigm(s1);
      float y2 = (s2 > 0.f) ? s2 : (__expf(s2) - 1.0f);
      out[(size_t)(b0 + tid) * KS_ + s] = y1;
      out[(size_t)B_ * KS_ + (size_t)(b0 + tid) * KS_ + s] = y2;
      x_lds[tid] = y1;
    }
    __syncthreads();  // (2) x + h visible before next step
  }
}

extern "C" void kernel_launch(void* const* d_in, const int* in_sizes, int n_in,
                              void* d_out, int out_size, void* d_ws, size_t ws_size,
                              hipStream_t stream) {
  const float* initial = (const float*)d_in[0];
  const float* enc_h   = (const float*)d_in[1];
  const float* enc_c   = (const float*)d_in[2];
  const float* Wx      = (const float*)d_in[3];
  const float* Wu      = (const float*)d_in[4];
  const float* bias    = (const float*)d_in[5];
  const float* w1      = (const float*)d_in[6];
  const float* b1      = (const float*)d_in[7];
  const float* w2      = (const float*)d_in[8];
  const float* b2      = (const float*)d_in[9];
  u16* pk = (u16*)d_ws;  // 2.06 MB packed [Wu; Wx; b] (bf16, MFMA B-frag order)

  pack_wu_kernel<<<528, 256, 0, stream>>>(Wu, Wx, bias, pk);
  lstm_kernel<<<256, 512, 0, stream>>>(initial, enc_h, enc_c, w1, b1,
                                       w2, b2, pk, (float*)d_out);
}

// Round 10
// 856.898 us; speedup vs baseline: 1.0203x; 1.0203x over previous
//
#include <hip/hip_runtime.h>

#define D_ 512
#define ND_ 2048   // 4*D
#define KS_ 24
#define TB_ 32
#define B_ 8192
#define NU_ 33     // 32 K-units of Wu + 1 ext unit [Wx; b]

typedef __attribute__((ext_vector_type(8))) short short8;
typedef __attribute__((ext_vector_type(16))) float f32x16;
typedef unsigned short u16;

// byte offset into swizzled h tile: row in [0,32), kb = byte offset along d (d*2)
#define SWZ(row, kb) (((row) * 1024) + ((kb) ^ (((row) & 15) << 4)))

__device__ __forceinline__ u16 f2bf(float f) {
  union { float f; unsigned int u; } v; v.f = f;
  unsigned int u = v.u;
  return (u16)((u + 0x7FFFu + ((u >> 16) & 1u)) >> 16);
}

__device__ __forceinline__ float sigm(float x) { return 1.0f / (1.0f + __expf(-x)); }
__device__ __forceinline__ float tanh_(float x) {
  float e = __expf(2.0f * x);
  return (e - 1.0f) / (e + 1.0f);
}

// async global->LDS, 16 B per lane; LDS dest is wave-uniform base + lane*16
__device__ __forceinline__ void glds16(const u16* g, void* l) {
  __builtin_amdgcn_global_load_lds(
      (const __attribute__((address_space(1))) unsigned int*)g,
      (__attribute__((address_space(3))) unsigned int*)l, 16, 0, 0);
}

// Pack [Wu; Wx; b] into MFMA B-fragment order, bf16. (unchanged from R8)
__global__ __launch_bounds__(256) void pack_wu_kernel(const float* __restrict__ Wu,
                                                      const float* __restrict__ Wx,
                                                      const float* __restrict__ b,
                                                      u16* __restrict__ pk) {
  int idx = blockIdx.x * 256 + threadIdx.x;
  int lane = idx & 63;
  int unit = idx >> 6;        // 0..2111 = nt*33 + un
  if (unit >= 64 * NU_) return;
  int nt = unit / NU_;
  int un = unit - nt * NU_;
  int col = nt * 32 + (lane & 31);
  u16 t[8] = {0, 0, 0, 0, 0, 0, 0, 0};
  if (un < 32) {
    int k0 = un * 16 + (lane >> 5) * 8;
#pragma unroll
    for (int j = 0; j < 8; ++j) t[j] = f2bf(Wu[(size_t)(k0 + j) * ND_ + col]);
  } else if ((lane >> 5) == 0) {
    t[0] = f2bf(Wx[col]);
    t[1] = f2bf(b[col]);
  }
  int4 w;
  w.x = t[0] | (t[1] << 16); w.y = t[2] | (t[3] << 16);
  w.z = t[4] | (t[5] << 16); w.w = t[6] | (t[7] << 16);
  *reinterpret_cast<int4*>(pk + (size_t)unit * 512 + lane * 8) = w;
}

// One pass over 33 K-units in BLOCK-ROTATED order (kc = (rot+ks)%33): all
// blocks cover the same set, but phase-shifted so the 32 CUs per XCD don't
// request the same L2 lines simultaneously (anti hot-lining). MFMA accumulate
// is order-independent, so the rotation only reorders the summation.
#define KSTEP_PASS(CREG, COL, W1V, W2V, A0, A1, A2, A3, X0, X1, X2, X3)        \
  {                                                                            \
    acc0 = (f32x16){}; acc1 = (f32x16){}; acc2 = (f32x16){}; acc3 = (f32x16){};\
    _Pragma("unroll 1")                                                        \
    for (int ks = 0; ks < 33; ++ks) {                                          \
      int kc = ks + rot; if (kc >= 33) kc -= 33;   /* consumed ring index */   \
      int ki = kc + 2;   if (ki >= 33) ki -= 33;   /* issued ring index  */    \
      const int swp = (ks + 2 >= 33);              /* issued is next pass */   \
      const size_t io = (size_t)ki * 512 + lofs8;                              \
      /* pb=0: issue pair(ki,0), wait, consume pair(kc,0) */                   \
      glds16((swp ? X0 : A0) + io, stg + slot_i * 2048);                       \
      glds16((swp ? X1 : A1) + io, stg + slot_i * 2048 + 1024);                \
      slot_i = (slot_i == 4) ? 0 : slot_i + 1;                                 \
      asm volatile("s_waitcnt vmcnt(8)" ::: "memory");                         \
      short8 a;                                                                \
      if (kc < 32) {                                                           \
        a = *reinterpret_cast<const short8*>(&hr[SWZ(l31, kc * 32 + abase)]);  \
      } else {                                                                 \
        short8 z8 = {};                                                        \
        if (lhi == 0) {                                                        \
          z8[0] = (short)f2bf(x_lds[l31]);                                     \
          z8[1] = (short)0x3F80;                                               \
        }                                                                      \
        a = z8;                                                                \
      }                                                                        \
      short8 f0 = *reinterpret_cast<const short8*>(stg + slot_c * 2048 + lofs);\
      short8 f1 = *reinterpret_cast<const short8*>(stg + slot_c * 2048 + 1024 + lofs);\
      slot_c = (slot_c == 4) ? 0 : slot_c + 1;                                 \
      acc0 = __builtin_amdgcn_mfma_f32_32x32x16_bf16(a, f0, acc0, 0, 0, 0);    \
      acc1 = __builtin_amdgcn_mfma_f32_32x32x16_bf16(a, f1, acc1, 0, 0, 0);    \
      /* pb=1 */                                                               \
      glds16((swp ? X2 : A2) + io, stg + slot_i * 2048);                       \
      glds16((swp ? X3 : A3) + io, stg + slot_i * 2048 + 1024);                \
      slot_i = (slot_i == 4) ? 0 : slot_i + 1;                                 \
      asm volatile("s_waitcnt vmcnt(8)" ::: "memory");                         \
      short8 f2 = *reinterpret_cast<const short8*>(stg + slot_c * 2048 + lofs);\
      short8 f3 = *reinterpret_cast<const short8*>(stg + slot_c * 2048 + 1024 + lofs);\
      slot_c = (slot_c == 4) ? 0 : slot_c + 1;                                 \
      acc2 = __builtin_amdgcn_mfma_f32_32x32x16_bf16(a, f2, acc2, 0, 0, 0);    \
      acc3 = __builtin_amdgcn_mfma_f32_32x32x16_bf16(a, f3, acc3, 0, 0, 0);    \
    }                                                                          \
    _Pragma("unroll")                                                          \
    for (int r = 0; r < 16; ++r) {                                             \
      const int row = (r & 3) + 8 * (r >> 2) + 4 * lhi;                        \
      float ig = sigm(acc0[r]);                                                \
      float fg = sigm(acc1[r]);                                                \
      float gg = tanh_(acc2[r]);                                               \
      float og = sigm(acc3[r]);                                                \
      float cn = fg * CREG[r] + ig * gg;                                       \
      CREG[r] = cn;                                                            \
      float hn = og * tanh_(cn);                                               \
      *reinterpret_cast<u16*>(&hw[SWZ(row, (COL) * 2)]) = f2bf(hn);            \
      y1p[r] += hn * (W1V);                                                    \
      y2p[r] += hn * (W2V);                                                    \
    }                                                                          \
  }

// 256 blocks x 512 threads (8 waves, 2 waves/SIMD, 256-reg budget, no spill).
// Identical to R9 except the block-rotated K-unit order (anti L2 hot-lining).
__global__ __launch_bounds__(512, 2) void lstm_kernel(
    const float* __restrict__ initial, const float* __restrict__ enc_h,
    const float* __restrict__ enc_c,
    const float* __restrict__ w1, const float* __restrict__ b1,
    const float* __restrict__ w2, const float* __restrict__ b2,
    const u16* __restrict__ wu, float* __restrict__ out) {
  __shared__ __align__(16) unsigned char hbuf[2][TB_ * 1024];   // 64 KB h dbuf
  __shared__ __align__(16) unsigned char wu_stage[8 * 5 * 2048]; // 80 KB ring
  __shared__ float x_lds[TB_];
  __shared__ float ly1[8][TB_];
  __shared__ float ly2[8][TB_];

  const int tid = threadIdx.x;
  const int wv  = tid >> 6;
  const int wvu = __builtin_amdgcn_readfirstlane(wv);  // wave-uniform -> SGPR
  const int l   = tid & 63;
  const int l31 = l & 31;
  const int lhi = l >> 5;
  const int b0  = blockIdx.x * TB_;
  const int rot = blockIdx.x % 33;   // per-block K-ring phase

  // ---- stage initial h (bf16, swizzled) into LDS: 512 threads ----
  {
    int row = tid >> 4;   // 0..31
    int seg = tid & 15;   // 32 cols each
    const float* src = enc_h + (size_t)(b0 + row) * D_ + seg * 32;
#pragma unroll
    for (int jb = 0; jb < 4; ++jb) {
      u16 t[8];
#pragma unroll
      for (int j = 0; j < 8; ++j) t[j] = f2bf(src[jb * 8 + j]);
      int kb = seg * 64 + jb * 16;
      int4 w;
      w.x = t[0] | (t[1] << 16); w.y = t[2] | (t[3] << 16);
      w.z = t[4] | (t[5] << 16); w.w = t[6] | (t[7] << 16);
      *reinterpret_cast<int4*>(&hbuf[0][SWZ(row, kb)]) = w;
    }
  }
  if (tid < TB_) x_lds[tid] = initial[b0 + tid];

  // ---- per-lane step-invariant values (2 passes) ----
  const int colA = wvu * 32 + l31;          // pass 0: n-tile wvu
  const int colB = (8 + wvu) * 32 + l31;    // pass 1: n-tile 8+wvu
  const float w1vA = w1[colA], w1vB = w1[colB];
  const float w2vA = w2[colA], w2vB = w2[colB];
  const float b1v = b1[0], b2v = b2[0];

  float cregA[16], cregB[16];
#pragma unroll
  for (int r = 0; r < 16; ++r) {
    const int row = (r & 3) + 8 * (r >> 2) + 4 * lhi;
    cregA[r] = enc_c[(size_t)(b0 + row) * D_ + colA];
    cregB[r] = enc_c[(size_t)(b0 + row) * D_ + colB];
  }

  // wave-uniform Wu stream bases: pass P, gate g -> n-tile g*16 + P*8 + wvu
  const u16* wA0 = wu + (size_t)(( 0 + wvu) * NU_) * 512;
  const u16* wA1 = wu + (size_t)((16 + wvu) * NU_) * 512;
  const u16* wA2 = wu + (size_t)((32 + wvu) * NU_) * 512;
  const u16* wA3 = wu + (size_t)((48 + wvu) * NU_) * 512;
  const u16* wB0 = wu + (size_t)(( 8 + wvu) * NU_) * 512;
  const u16* wB1 = wu + (size_t)((24 + wvu) * NU_) * 512;
  const u16* wB2 = wu + (size_t)((40 + wvu) * NU_) * 512;
  const u16* wB3 = wu + (size_t)((56 + wvu) * NU_) * 512;
  const size_t lofs8 = (size_t)l * 8;
  const int lofs = l * 16;
  const int abase = lhi * 16;
  unsigned char* stg = &wu_stage[wvu * 10240];  // 5 slots x 2 KB

  __syncthreads();
  asm volatile("s_waitcnt vmcnt(0)" ::: "memory");  // drain creg/h loads

  // prologue: issue ring elements rot, rot+1 (pass 0, both gate-pairs)
  {
    const size_t q0 = (size_t)rot * 512 + lofs8;
    const size_t q1 = (size_t)((rot + 1 == 33) ? 0 : rot + 1) * 512 + lofs8;
    glds16(wA0 + q0, stg);
    glds16(wA1 + q0, stg + 1024);
    glds16(wA2 + q0, stg + 2048);
    glds16(wA3 + q0, stg + 3072);
    glds16(wA0 + q1, stg + 4096);
    glds16(wA1 + q1, stg + 5120);
    glds16(wA2 + q1, stg + 6144);
    glds16(wA3 + q1, stg + 7168);
  }
  int slot_i = 4, slot_c = 0;

  for (int s = 0; s < KS_; ++s) {
    const unsigned char* hr = hbuf[s & 1];
    unsigned char* hw = hbuf[(s & 1) ^ 1];

    float y1p[16], y2p[16];
#pragma unroll
    for (int r = 0; r < 16; ++r) { y1p[r] = 0.f; y2p[r] = 0.f; }

    f32x16 acc0, acc1, acc2, acc3;
    // pass 0 (issue cursor rolls into pass-1 bases near the end)
    KSTEP_PASS(cregA, colA, w1vA, w2vA, wA0, wA1, wA2, wA3, wB0, wB1, wB2, wB3)
    // pass 1 (issue cursor wraps into pass-0 bases = next step's first pairs)
    KSTEP_PASS(cregB, colB, w1vB, w2vB, wB0, wB1, wB2, wB3, wA0, wA1, wA2, wA3)

    // reduce y partials across the 32 lanes of each half-wave
#pragma unroll
    for (int m = 1; m < 32; m <<= 1) {
#pragma unroll
      for (int r = 0; r < 16; ++r) {
        y1p[r] += __shfl_xor(y1p[r], m);
        y2p[r] += __shfl_xor(y2p[r], m);
      }
    }
    if (l31 == 0) {
#pragma unroll
      for (int r = 0; r < 16; ++r) {
        const int row = (r & 3) + 8 * (r >> 2) + 4 * lhi;
        ly1[wvu][row] = y1p[r];
        ly2[wvu][row] = y2p[r];
      }
    }
    __syncthreads();  // (1) ly slots + new h complete

    if (tid < TB_) {
      float s1 = b1v, s2 = b2v;
#pragma unroll
      for (int wq = 0; wq < 8; ++wq) { s1 += ly1[wq][tid]; s2 += ly2[wq][tid]; }
      float y1 = sigm(s1);
      float y2 = (s2 > 0.f) ? s2 : (__expf(s2) - 1.0f);
      out[(size_t)(b0 + tid) * KS_ + s] = y1;
      out[(size_t)B_ * KS_ + (size_t)(b0 + tid) * KS_ + s] = y2;
      x_lds[tid] = y1;
    }
    __syncthreads();  // (2) x + h visible before next step
  }
}

extern "C" void kernel_launch(void* const* d_in, const int* in_sizes, int n_in,
                              void* d_out, int out_size, void* d_ws, size_t ws_size,
                              hipStream_t stream) {
  const float* initial = (const float*)d_in[0];
  const float* enc_h   = (const float*)d_in[1];
  const float* enc_c   = (const float*)d_in[2];
  const float* Wx      = (const float*)d_in[3];
  const float* Wu      = (const float*)d_in[4];
  const float* bias    = (const float*)d_in[5];
  const float* w1      = (const float*)d_in[6];
  const float* b1      = (const float*)d_in[7];
  const float* w2      = (const float*)d_in[8];
  const float* b2      = (const float*)d_in[9];
  u16* pk = (u16*)d_ws;  // 2.06 MB packed [Wu; Wx; b] (bf16, MFMA B-frag order)

  pack_wu_kernel<<<528, 256, 0, stream>>>(Wu, Wx, bias, pk);
  lstm_kernel<<<256, 512, 0, stream>>>(initial, enc_h, enc_c, w1, b1,
                                       w2, b2, pk, (float*)d_out);
}

// Round 11
// 682.749 us; speedup vs baseline: 1.2805x; 1.2551x over previous
//
#include <hip/hip_runtime.h>

#define D_ 512
#define ND_ 2048   // 4*D
#define KS_ 24
#define TB_ 32
#define B_ 8192
#define NU_ 33     // 32 K-units of Wu + 1 ext unit [Wx; b]

typedef __attribute__((ext_vector_type(8))) short short8;
typedef __attribute__((ext_vector_type(16))) float f32x16;
typedef unsigned short u16;

// byte offset into swizzled h tile: row in [0,32), kb = byte offset along d (d*2)
#define SWZ(row, kb) (((row) * 1024) + ((kb) ^ (((row) & 15) << 4)))

__device__ __forceinline__ u16 f2bf(float f) {
  union { float f; unsigned int u; } v; v.f = f;
  unsigned int u = v.u;
  return (u16)((u + 0x7FFFu + ((u >> 16) & 1u)) >> 16);
}

__device__ __forceinline__ float sigm(float x) { return 1.0f / (1.0f + __expf(-x)); }
__device__ __forceinline__ float tanh_(float x) {
  float e = __expf(2.0f * x);
  return (e - 1.0f) / (e + 1.0f);
}

// Pack [Wu; Wx; b] into MFMA B-fragment order, bf16. (unchanged from R8)
__global__ __launch_bounds__(256) void pack_wu_kernel(const float* __restrict__ Wu,
                                                      const float* __restrict__ Wx,
                                                      const float* __restrict__ b,
                                                      u16* __restrict__ pk) {
  int idx = blockIdx.x * 256 + threadIdx.x;
  int lane = idx & 63;
  int unit = idx >> 6;        // 0..2111 = nt*33 + un
  if (unit >= 64 * NU_) return;
  int nt = unit / NU_;
  int un = unit - nt * NU_;
  int col = nt * 32 + (lane & 31);
  u16 t[8] = {0, 0, 0, 0, 0, 0, 0, 0};
  if (un < 32) {
    int k0 = un * 16 + (lane >> 5) * 8;
#pragma unroll
    for (int j = 0; j < 8; ++j) t[j] = f2bf(Wu[(size_t)(k0 + j) * ND_ + col]);
  } else if ((lane >> 5) == 0) {
    t[0] = f2bf(Wx[col]);
    t[1] = f2bf(b[col]);
  }
  int4 w;
  w.x = t[0] | (t[1] << 16); w.y = t[2] | (t[3] << 16);
  w.z = t[4] | (t[5] << 16); w.w = t[6] | (t[7] << 16);
  *reinterpret_cast<int4*>(pk + (size_t)unit * 512 + lane * 8) = w;
}

#define LD8(P, u) (*reinterpret_cast<const short8*>((P) + (size_t)(u) * 512))

// One pass = 33 K-units (32 Wu + 1 ext) for one n-tile per gate, register
// ping-pong: fB loads issue before the MFMAs consuming fA and vice versa, so
// the compiler keeps ~8 KB/wave of plain global loads in flight (no glds, no
// inline-asm vmcnt — compiler-managed waits, m97-style).
#define KSTEP_PASS(CREG, COL, W1V, W2V, P0, P1, P2, P3)                        \
  {                                                                            \
    acc0 = (f32x16){}; acc1 = (f32x16){}; acc2 = (f32x16){}; acc3 = (f32x16){};\
    short8 fA0 = LD8(P0, 0), fA1 = LD8(P1, 0), fA2 = LD8(P2, 0), fA3 = LD8(P3, 0);\
    short8 fB0, fB1, fB2, fB3;                                                 \
    _Pragma("unroll 1")                                                        \
    for (int ks = 0; ks < 32; ks += 2) {                                       \
      fB0 = LD8(P0, ks + 1); fB1 = LD8(P1, ks + 1);                            \
      fB2 = LD8(P2, ks + 1); fB3 = LD8(P3, ks + 1);                            \
      short8 a0 = *reinterpret_cast<const short8*>(&hr[SWZ(l31, ks * 32 + abase)]);\
      acc0 = __builtin_amdgcn_mfma_f32_32x32x16_bf16(a0, fA0, acc0, 0, 0, 0);  \
      acc1 = __builtin_amdgcn_mfma_f32_32x32x16_bf16(a0, fA1, acc1, 0, 0, 0);  \
      acc2 = __builtin_amdgcn_mfma_f32_32x32x16_bf16(a0, fA2, acc2, 0, 0, 0);  \
      acc3 = __builtin_amdgcn_mfma_f32_32x32x16_bf16(a0, fA3, acc3, 0, 0, 0);  \
      fA0 = LD8(P0, ks + 2); fA1 = LD8(P1, ks + 2);  /* ks+2==32 -> ext unit */\
      fA2 = LD8(P2, ks + 2); fA3 = LD8(P3, ks + 2);                            \
      short8 a1 = *reinterpret_cast<const short8*>(&hr[SWZ(l31, (ks + 1) * 32 + abase)]);\
      acc0 = __builtin_amdgcn_mfma_f32_32x32x16_bf16(a1, fB0, acc0, 0, 0, 0);  \
      acc1 = __builtin_amdgcn_mfma_f32_32x32x16_bf16(a1, fB1, acc1, 0, 0, 0);  \
      acc2 = __builtin_amdgcn_mfma_f32_32x32x16_bf16(a1, fB2, acc2, 0, 0, 0);  \
      acc3 = __builtin_amdgcn_mfma_f32_32x32x16_bf16(a1, fB3, acc3, 0, 0, 0);  \
    }                                                                          \
    { /* ext slice: h_ext = [x, 1, 0...], fA holds unit 32 */                  \
      short8 ax = {};                                                          \
      if (lhi == 0) {                                                          \
        ax[0] = (short)f2bf(x_lds[l31]);                                       \
        ax[1] = (short)0x3F80;                                                 \
      }                                                                        \
      acc0 = __builtin_amdgcn_mfma_f32_32x32x16_bf16(ax, fA0, acc0, 0, 0, 0);  \
      acc1 = __builtin_amdgcn_mfma_f32_32x32x16_bf16(ax, fA1, acc1, 0, 0, 0);  \
      acc2 = __builtin_amdgcn_mfma_f32_32x32x16_bf16(ax, fA2, acc2, 0, 0, 0);  \
      acc3 = __builtin_amdgcn_mfma_f32_32x32x16_bf16(ax, fA3, acc3, 0, 0, 0);  \
    }                                                                          \
    _Pragma("unroll")                                                          \
    for (int r = 0; r < 16; ++r) {                                             \
      const int row = (r & 3) + 8 * (r >> 2) + 4 * lhi;                        \
      float ig = sigm(acc0[r]);                                                \
      float fg = sigm(acc1[r]);                                                \
      float gg = tanh_(acc2[r]);                                               \
      float og = sigm(acc3[r]);                                                \
      float cn = fg * CREG[r] + ig * gg;                                       \
      CREG[r] = cn;                                                            \
      float hn = og * tanh_(cn);                                               \
      *reinterpret_cast<u16*>(&hw[SWZ(row, (COL) * 2)]) = f2bf(hn);            \
      y1p[r] += hn * (W1V);                                                    \
      y2p[r] += hn * (W2V);                                                    \
    }                                                                          \
  }

// 256 blocks x 512 threads (8 waves, 2 waves/SIMD -> 256-reg budget).
// Two sequential n-tile passes per wave (acc reused, 64 AGPR). B-fragments
// via plain register loads with ping-pong (compiler-managed in-flight).
__global__ __launch_bounds__(512, 2) void lstm_kernel(
    const float* __restrict__ initial, const float* __restrict__ enc_h,
    const float* __restrict__ enc_c,
    const float* __restrict__ w1, const float* __restrict__ b1,
    const float* __restrict__ w2, const float* __restrict__ b2,
    const u16* __restrict__ wu, float* __restrict__ out) {
  __shared__ __align__(16) unsigned char hbuf[2][TB_ * 1024];   // 64 KB h dbuf
  __shared__ float x_lds[TB_];
  __shared__ float ly1[8][TB_];
  __shared__ float ly2[8][TB_];

  const int tid = threadIdx.x;
  const int wv  = tid >> 6;
  const int wvu = __builtin_amdgcn_readfirstlane(wv);  // wave-uniform -> SGPR
  const int l   = tid & 63;
  const int l31 = l & 31;
  const int lhi = l >> 5;
  const int b0  = blockIdx.x * TB_;

  // ---- stage initial h (bf16, swizzled) into LDS: 512 threads ----
  {
    int row = tid >> 4;   // 0..31
    int seg = tid & 15;   // 32 cols each
    const float* src = enc_h + (size_t)(b0 + row) * D_ + seg * 32;
#pragma unroll
    for (int jb = 0; jb < 4; ++jb) {
      u16 t[8];
#pragma unroll
      for (int j = 0; j < 8; ++j) t[j] = f2bf(src[jb * 8 + j]);
      int kb = seg * 64 + jb * 16;
      int4 w;
      w.x = t[0] | (t[1] << 16); w.y = t[2] | (t[3] << 16);
      w.z = t[4] | (t[5] << 16); w.w = t[6] | (t[7] << 16);
      *reinterpret_cast<int4*>(&hbuf[0][SWZ(row, kb)]) = w;
    }
  }
  if (tid < TB_) x_lds[tid] = initial[b0 + tid];

  // ---- per-lane step-invariant values (2 passes) ----
  const int colA = wvu * 32 + l31;          // pass 0: n-tile wvu
  const int colB = (8 + wvu) * 32 + l31;    // pass 1: n-tile 8+wvu
  const float w1vA = w1[colA], w1vB = w1[colB];
  const float w2vA = w2[colA], w2vB = w2[colB];
  const float b1v = b1[0], b2v = b2[0];

  float cregA[16], cregB[16];
#pragma unroll
  for (int r = 0; r < 16; ++r) {
    const int row = (r & 3) + 8 * (r >> 2) + 4 * lhi;
    cregA[r] = enc_c[(size_t)(b0 + row) * D_ + colA];
    cregB[r] = enc_c[(size_t)(b0 + row) * D_ + colB];
  }

  // per-lane stream pointers: pass P, gate g -> n-tile g*16 + P*8 + wvu
  const size_t lofs8 = (size_t)l * 8;
  const u16* pA0 = wu + (size_t)(( 0 + wvu) * NU_) * 512 + lofs8;
  const u16* pA1 = wu + (size_t)((16 + wvu) * NU_) * 512 + lofs8;
  const u16* pA2 = wu + (size_t)((32 + wvu) * NU_) * 512 + lofs8;
  const u16* pA3 = wu + (size_t)((48 + wvu) * NU_) * 512 + lofs8;
  const u16* pB0 = wu + (size_t)(( 8 + wvu) * NU_) * 512 + lofs8;
  const u16* pB1 = wu + (size_t)((24 + wvu) * NU_) * 512 + lofs8;
  const u16* pB2 = wu + (size_t)((40 + wvu) * NU_) * 512 + lofs8;
  const u16* pB3 = wu + (size_t)((56 + wvu) * NU_) * 512 + lofs8;
  const int abase = lhi * 16;

  __syncthreads();

  for (int s = 0; s < KS_; ++s) {
    const unsigned char* hr = hbuf[s & 1];
    unsigned char* hw = hbuf[(s & 1) ^ 1];

    float y1p[16], y2p[16];
#pragma unroll
    for (int r = 0; r < 16; ++r) { y1p[r] = 0.f; y2p[r] = 0.f; }

    f32x16 acc0, acc1, acc2, acc3;
    KSTEP_PASS(cregA, colA, w1vA, w2vA, pA0, pA1, pA2, pA3)
    KSTEP_PASS(cregB, colB, w1vB, w2vB, pB0, pB1, pB2, pB3)

    // reduce y partials across the 32 lanes of each half-wave
#pragma unroll
    for (int m = 1; m < 32; m <<= 1) {
#pragma unroll
      for (int r = 0; r < 16; ++r) {
        y1p[r] += __shfl_xor(y1p[r], m);
        y2p[r] += __shfl_xor(y2p[r], m);
      }
    }
    if (l31 == 0) {
#pragma unroll
      for (int r = 0; r < 16; ++r) {
        const int row = (r & 3) + 8 * (r >> 2) + 4 * lhi;
        ly1[wvu][row] = y1p[r];
        ly2[wvu][row] = y2p[r];
      }
    }
    __syncthreads();  // (1) ly slots + new h complete

    if (tid < TB_) {
      float s1 = b1v, s2 = b2v;
#pragma unroll
      for (int wq = 0; wq < 8; ++wq) { s1 += ly1[wq][tid]; s2 += ly2[wq][tid]; }
      float y1 = sigm(s1);
      float y2 = (s2 > 0.f) ? s2 : (__expf(s2) - 1.0f);
      out[(size_t)(b0 + tid) * KS_ + s] = y1;
      out[(size_t)B_ * KS_ + (size_t)(b0 + tid) * KS_ + s] = y2;
      x_lds[tid] = y1;
    }
    __syncthreads();  // (2) x + h visible before next step
  }
}

extern "C" void kernel_launch(void* const* d_in, const int* in_sizes, int n_in,
                              void* d_out, int out_size, void* d_ws, size_t ws_size,
                              hipStream_t stream) {
  const float* initial = (const float*)d_in[0];
  const float* enc_h   = (const float*)d_in[1];
  const float* enc_c   = (const float*)d_in[2];
  const float* Wx      = (const float*)d_in[3];
  const float* Wu      = (const float*)d_in[4];
  const float* bias    = (const float*)d_in[5];
  const float* w1      = (const float*)d_in[6];
  const float* b1      = (const float*)d_in[7];
  const float* w2      = (const float*)d_in[8];
  const float* b2      = (const float*)d_in[9];
  u16* pk = (u16*)d_ws;  // 2.06 MB packed [Wu; Wx; b] (bf16, MFMA B-frag order)

  pack_wu_kernel<<<528, 256, 0, stream>>>(Wu, Wx, bias, pk);
  lstm_kernel<<<256, 512, 0, stream>>>(initial, enc_h, enc_c, w1, b1,
                                       w2, b2, pk, (float*)d_out);
}